// Round 1
// baseline (350.900 us; speedup 1.0000x reference)
//
#include <hip/hip_runtime.h>
#include <hip/hip_bf16.h>

// Problem constants (B=4, N=4096, D=1024, H=16, hd=64, G=512, sigma=3)
#define NPOS 4096
#define DIM  1024
#define GSZ  512
#define JMAX 96

#define GAS __attribute__((address_space(1)))
#define LAS __attribute__((address_space(3)))

typedef __attribute__((ext_vector_type(8))) short bf16x8;   // 8 bf16 (4 VGPRs)
typedef __attribute__((ext_vector_type(4))) float f32x4;

__device__ __forceinline__ void async_load16(const void* g, void* l) {
  __builtin_amdgcn_global_load_lds((const GAS void*)g, (LAS void*)l, 16, 0, 0);
}

// Bit-exact replica of np: (arange(N,f32)/4095)*511 then trunc-to-int32.
__device__ __forceinline__ int fidx_of(int n) {
  return (int)(((float)n / 4095.0f) * 511.0f);
}

// ---------------- cast f32 -> bf16, 4 elems/thread ----------------
__global__ __launch_bounds__(256) void cast_f32_to_bf16(
    const float* __restrict__ src, __hip_bfloat16* __restrict__ dst, int n) {
  int i = (blockIdx.x * 256 + threadIdx.x) * 4;
  if (i < n) {
    float4 f = *(const float4*)(src + i);
    ushort4 o;
    __hip_bfloat16 t;
    t = __float2bfloat16(f.x); o.x = *(unsigned short*)&t;
    t = __float2bfloat16(f.y); o.y = *(unsigned short*)&t;
    t = __float2bfloat16(f.z); o.z = *(unsigned short*)&t;
    t = __float2bfloat16(f.w); o.w = *(unsigned short*)&t;
    *(ushort4*)(dst + i) = o;
  }
}

// ---------------- 128x128-tile bf16 MFMA GEMM (NT: C = A @ B^T) ----------------
// A: M x K row-major (optionally row-remapped via field_idx gather)
// B: N x K row-major; bias per column (two pointers: cols<1024 -> bias0)
template<bool REMAP, bool OUTBF16>
__global__ __launch_bounds__(256) void gemm_bt(
    const __hip_bfloat16* __restrict__ A,
    const __hip_bfloat16* __restrict__ B,
    const float* __restrict__ bias0, const float* __restrict__ bias1,
    void* __restrict__ Cv, int N) {
  const int K = 1024;
  __shared__ __align__(16) __hip_bfloat16 As[128 * 32];
  __shared__ __align__(16) __hip_bfloat16 Bs[128 * 32];
  const int tid = threadIdx.x;
  const int bm = blockIdx.x * 128, bn = blockIdx.y * 128;

  // staging: 256 threads x 16B = 4KB/inst; 2 insts each for A,B (128x32 bf16 = 8KB)
  const int srow = tid >> 2;          // 0..63
  const int scol = (tid & 3) * 8;     // 0,8,16,24
  int ar0 = bm + srow, ar1 = bm + srow + 64;
  if (REMAP) {  // A row i=(b,n) -> conv row b*512 + field_idx(n)
    int b0 = ar0 >> 12, n0 = ar0 & (NPOS - 1);
    ar0 = b0 * GSZ + fidx_of(n0);
    int b1 = ar1 >> 12, n1 = ar1 & (NPOS - 1);
    ar1 = b1 * GSZ + fidx_of(n1);
  }
  const __hip_bfloat16* ap0 = A + (size_t)ar0 * K + scol;
  const __hip_bfloat16* ap1 = A + (size_t)ar1 * K + scol;
  const __hip_bfloat16* bp0 = B + (size_t)(bn + srow) * K + scol;
  const __hip_bfloat16* bp1 = B + (size_t)(bn + srow + 64) * K + scol;
  __hip_bfloat16* as0 = &As[srow * 32 + scol];        // = As + tid*8 elems -> lane*16B
  __hip_bfloat16* as1 = &As[(srow + 64) * 32 + scol];
  __hip_bfloat16* bs0 = &Bs[srow * 32 + scol];
  __hip_bfloat16* bs1 = &Bs[(srow + 64) * 32 + scol];

  const int wave = tid >> 6, lane = tid & 63;
  const int wm = (wave >> 1) * 64, wn = (wave & 1) * 64;
  const int m16 = lane & 15, quad = lane >> 4;

  f32x4 acc[4][4];
#pragma unroll
  for (int i = 0; i < 4; i++)
#pragma unroll
    for (int j = 0; j < 4; j++) acc[i][j] = (f32x4)0.f;

  for (int k0 = 0; k0 < K; k0 += 32) {
    async_load16(ap0 + k0, as0);
    async_load16(ap1 + k0, as1);
    async_load16(bp0 + k0, bs0);
    async_load16(bp1 + k0, bs1);
    __syncthreads();   // compiler drains vmcnt before barrier
    bf16x8 af[4], bfr[4];
#pragma unroll
    for (int mt = 0; mt < 4; mt++)
      af[mt] = *(const bf16x8*)&As[(wm + mt * 16 + m16) * 32 + quad * 8];
#pragma unroll
    for (int nt = 0; nt < 4; nt++)
      bfr[nt] = *(const bf16x8*)&Bs[(wn + nt * 16 + m16) * 32 + quad * 8];
#pragma unroll
    for (int mt = 0; mt < 4; mt++)
#pragma unroll
      for (int nt = 0; nt < 4; nt++)
        acc[mt][nt] = __builtin_amdgcn_mfma_f32_16x16x32_bf16(af[mt], bfr[nt], acc[mt][nt], 0, 0, 0);
    __syncthreads();
  }

  // epilogue: C/D layout col=lane&15, row=quad*4+reg (m89/m91-verified)
#pragma unroll
  for (int mt = 0; mt < 4; mt++) {
#pragma unroll
    for (int nt = 0; nt < 4; nt++) {
      int col = bn + wn + nt * 16 + m16;
      float bv = (col < 1024) ? bias0[col] : bias1[col - 1024];
#pragma unroll
      for (int r = 0; r < 4; r++) {
        int row = bm + wm + mt * 16 + quad * 4 + r;
        float v = acc[mt][nt][r] + bv;
        if (OUTBF16)
          ((__hip_bfloat16*)Cv)[(size_t)row * N + col] = __float2bfloat16(v);
        else
          ((float*)Cv)[(size_t)row * N + col] = v;
      }
    }
  }
}

// ---------------- field: segment-sum of v * ||k|| into G bins ----------------
// KV: (16384, 2048) bf16; cols 0..1023 = k, 1024..2047 = v.  field: (B,G,D) f32
__global__ __launch_bounds__(256) void wv_field_kernel(
    const __hip_bfloat16* __restrict__ KV, float* __restrict__ field) {
  const int b = blockIdx.x, g = blockIdx.y;
  // contiguous row range [i0,i1) of this bin, derived from the exact f32 formula
  int i0 = (g * 4095 + 510) / 511;
  while (i0 > 0 && fidx_of(i0 - 1) >= g) --i0;
  while (i0 < NPOS && fidx_of(i0) < g) ++i0;
  int i1;
  if (g == GSZ - 1) i1 = NPOS;
  else {
    i1 = ((g + 1) * 4095 + 510) / 511;
    while (i1 > 0 && fidx_of(i1 - 1) >= g + 1) --i1;
    while (i1 < NPOS && fidx_of(i1) < g + 1) ++i1;
  }
  int cnt = i1 - i0;                 // 8 or 9
  if (cnt > 12) cnt = 12;
  __shared__ float km[12][16];       // [row][head]
  const int tid = threadIdx.x;
  if (tid < cnt * 16) {
    int r = tid >> 4, h = tid & 15;
    const __hip_bfloat16* kp = KV + (size_t)(b * NPOS + i0 + r) * 2048 + h * 64;
    float s = 0.f;
    for (int e = 0; e < 64; ++e) { float kv = (float)kp[e]; s += kv * kv; }
    km[r][h] = sqrtf(s);
  }
  __syncthreads();
  for (int c = tid; c < DIM; c += 256) {
    int h = c >> 6;
    float acc = 0.f;
    for (int r = 0; r < cnt; ++r)
      acc += km[r][h] * (float)KV[(size_t)(b * NPOS + i0 + r) * 2048 + 1024 + c];
    field[((size_t)(b * GSZ + g)) * DIM + c] = acc;
  }
}

// ---------------- causal-kernel circular conv (96 taps), out bf16 ----------------
// conv[n] = sum_{j=1..JMAX} e^{-j/3}/S * field[(n + 256 + j) & 511]
__global__ __launch_bounds__(256) void conv_kernel(
    const float* __restrict__ field, __hip_bfloat16* __restrict__ convb) {
  const int b = blockIdx.x, h = blockIdx.y, g0 = blockIdx.z * 128;
  __shared__ float slab[223 * 64];
  __shared__ float w[JMAX + 1];
  const int tid = threadIdx.x;
  if (tid >= 1 && tid <= JMAX) {
    float S = 0.f;
    for (int j = 256; j >= 1; --j) S += expf(-(float)j / 3.0f);  // ascending magnitude
    S += 1e-8f;
    w[tid] = expf(-(float)tid / 3.0f) / S;
  }
  for (int s = tid; s < 223 * 64; s += 256) {
    int tr = s >> 6, c = s & 63;
    int gg = (g0 + 257 + tr) & (GSZ - 1);
    slab[s] = field[((size_t)(b * GSZ + gg)) * DIM + h * 64 + c];
  }
  __syncthreads();
  for (int o = tid; o < 128 * 64; o += 256) {
    int u = o >> 6, c = o & 63;
    float acc = 0.f;
#pragma unroll 8
    for (int j = 1; j <= JMAX; ++j)
      acc += w[j] * slab[(u + j - 1) * 64 + c];
    convb[((size_t)(b * GSZ + g0 + u)) * DIM + h * 64 + c] = __float2bfloat16(acc);
  }
}

extern "C" void kernel_launch(void* const* d_in, const int* in_sizes, int n_in,
                              void* d_out, int out_size, void* d_ws, size_t ws_size,
                              hipStream_t stream) {
  (void)in_sizes; (void)n_in; (void)out_size; (void)ws_size;
  const float* x     = (const float*)d_in[0];
  // d_in[1]=q_w, d_in[2]=q_b: dead in the reference — skipped.
  const float* k_w   = (const float*)d_in[3];
  const float* k_b   = (const float*)d_in[4];
  const float* v_w   = (const float*)d_in[5];
  const float* v_b   = (const float*)d_in[6];
  const float* out_w = (const float*)d_in[7];
  const float* out_b = (const float*)d_in[8];

  char* p = (char*)d_ws;
  __hip_bfloat16* xb    = (__hip_bfloat16*)p; p += (size_t)16384 * 1024 * 2;  // 32 MB
  __hip_bfloat16* kvwb  = (__hip_bfloat16*)p; p += (size_t)2048 * 1024 * 2;   // 4 MB
  __hip_bfloat16* outwb = (__hip_bfloat16*)p; p += (size_t)1024 * 1024 * 2;   // 2 MB
  __hip_bfloat16* KV    = (__hip_bfloat16*)p; p += (size_t)16384 * 2048 * 2;  // 64 MB
  float*          field = (float*)p;          p += (size_t)4 * 512 * 1024 * 4;// 8 MB
  __hip_bfloat16* convb = (__hip_bfloat16*)p;                                 // 4 MB

  cast_f32_to_bf16<<<16384, 256, 0, stream>>>(x, xb, 16384 * 1024);
  cast_f32_to_bf16<<<1024, 256, 0, stream>>>(k_w, kvwb, 1024 * 1024);
  cast_f32_to_bf16<<<1024, 256, 0, stream>>>(v_w, kvwb + 1024 * 1024, 1024 * 1024);
  cast_f32_to_bf16<<<1024, 256, 0, stream>>>(out_w, outwb, 1024 * 1024);

  // fused K+V projection: (16384x1024) @ (2048x1024)^T -> KV bf16
  gemm_bt<false, true><<<dim3(128, 16), 256, 0, stream>>>(xb, kvwb, k_b, v_b, KV, 2048);

  wv_field_kernel<<<dim3(4, 512), 256, 0, stream>>>(KV, field);
  conv_kernel<<<dim3(4, 16, 4), 256, 0, stream>>>(field, convb);

  // output GEMM with fused conv-row gather: C = conv[fidx] @ out_w^T + out_b -> f32 d_out
  gemm_bt<true, false><<<dim3(128, 8), 256, 0, stream>>>(convb, outwb, out_b, out_b, (float*)d_out, 1024);
}

// Round 2
// 296.064 us; speedup vs baseline: 1.1852x; 1.1852x over previous
//
#include <hip/hip_runtime.h>
#include <hip/hip_bf16.h>

// Problem constants (B=4, N=4096, D=1024, H=16, hd=64, G=512, sigma=3)
#define NPOS 4096
#define DIM  1024
#define GSZ  512

#define GAS __attribute__((address_space(1)))
#define LAS __attribute__((address_space(3)))

typedef __attribute__((ext_vector_type(8))) short bf16x8;   // 8 bf16 (4 VGPRs)
typedef __attribute__((ext_vector_type(4))) float f32x4;

__device__ __forceinline__ void async_load16(const void* g, void* l) {
  __builtin_amdgcn_global_load_lds((const GAS void*)g, (LAS void*)l, 16, 0, 0);
}

// Bit-exact replica of np: (arange(N,f32)/4095)*511 then trunc-to-int32.
__device__ __forceinline__ int fidx_of(int n) {
  return (int)(((float)n / 4095.0f) * 511.0f);
}

__device__ __forceinline__ float bf2f(unsigned short s) {
  union { unsigned u; float f; } v; v.u = ((unsigned)s) << 16; return v.f;
}

// ---------------- cast f32 -> bf16, 4 elems/thread ----------------
__global__ __launch_bounds__(256) void cast_f32_to_bf16(
    const float* __restrict__ src, __hip_bfloat16* __restrict__ dst, int n) {
  int i = (blockIdx.x * 256 + threadIdx.x) * 4;
  if (i < n) {
    float4 f = *(const float4*)(src + i);
    ushort4 o;
    __hip_bfloat16 t;
    t = __float2bfloat16(f.x); o.x = *(unsigned short*)&t;
    t = __float2bfloat16(f.y); o.y = *(unsigned short*)&t;
    t = __float2bfloat16(f.z); o.z = *(unsigned short*)&t;
    t = __float2bfloat16(f.w); o.w = *(unsigned short*)&t;
    *(ushort4*)(dst + i) = o;
  }
}

// ---------------- 128x128-tile bf16 MFMA GEMM (NT: C = A @ B^T) ----------------
// A: M x K row-major; B: N x K row-major; bias per column (cols<1024 -> bias0)
template<bool OUTBF16>
__global__ __launch_bounds__(256) void gemm_bt(
    const __hip_bfloat16* __restrict__ A,
    const __hip_bfloat16* __restrict__ B,
    const float* __restrict__ bias0, const float* __restrict__ bias1,
    void* __restrict__ Cv, int N) {
  const int K = 1024;
  __shared__ __align__(16) __hip_bfloat16 As[128 * 32];
  __shared__ __align__(16) __hip_bfloat16 Bs[128 * 32];
  const int tid = threadIdx.x;
  const int bm = blockIdx.x * 128, bn = blockIdx.y * 128;

  // staging: 256 threads x 16B = 4KB/inst; 2 insts each for A,B (128x32 bf16 = 8KB)
  const int srow = tid >> 2;          // 0..63
  const int scol = (tid & 3) * 8;     // 0,8,16,24
  const __hip_bfloat16* ap0 = A + (size_t)(bm + srow) * K + scol;
  const __hip_bfloat16* ap1 = A + (size_t)(bm + srow + 64) * K + scol;
  const __hip_bfloat16* bp0 = B + (size_t)(bn + srow) * K + scol;
  const __hip_bfloat16* bp1 = B + (size_t)(bn + srow + 64) * K + scol;
  __hip_bfloat16* as0 = &As[srow * 32 + scol];        // lane-ordered: tid*16B
  __hip_bfloat16* as1 = &As[(srow + 64) * 32 + scol];
  __hip_bfloat16* bs0 = &Bs[srow * 32 + scol];
  __hip_bfloat16* bs1 = &Bs[(srow + 64) * 32 + scol];

  const int wave = tid >> 6, lane = tid & 63;
  const int wm = (wave >> 1) * 64, wn = (wave & 1) * 64;
  const int m16 = lane & 15, quad = lane >> 4;

  f32x4 acc[4][4];
#pragma unroll
  for (int i = 0; i < 4; i++)
#pragma unroll
    for (int j = 0; j < 4; j++) acc[i][j] = (f32x4)0.f;

  for (int k0 = 0; k0 < K; k0 += 32) {
    async_load16(ap0 + k0, as0);
    async_load16(ap1 + k0, as1);
    async_load16(bp0 + k0, bs0);
    async_load16(bp1 + k0, bs1);
    __syncthreads();   // compiler drains vmcnt before barrier
    bf16x8 af[4], bfr[4];
#pragma unroll
    for (int mt = 0; mt < 4; mt++)
      af[mt] = *(const bf16x8*)&As[(wm + mt * 16 + m16) * 32 + quad * 8];
#pragma unroll
    for (int nt = 0; nt < 4; nt++)
      bfr[nt] = *(const bf16x8*)&Bs[(wn + nt * 16 + m16) * 32 + quad * 8];
#pragma unroll
    for (int mt = 0; mt < 4; mt++)
#pragma unroll
      for (int nt = 0; nt < 4; nt++)
        acc[mt][nt] = __builtin_amdgcn_mfma_f32_16x16x32_bf16(af[mt], bfr[nt], acc[mt][nt], 0, 0, 0);
    __syncthreads();
  }

  // epilogue: C/D layout col=lane&15, row=quad*4+reg (m89/m91-verified)
#pragma unroll
  for (int mt = 0; mt < 4; mt++) {
#pragma unroll
    for (int nt = 0; nt < 4; nt++) {
      int col = bn + wn + nt * 16 + m16;
      float bv = (col < 1024) ? bias0[col] : bias1[col - 1024];
#pragma unroll
      for (int r = 0; r < 4; r++) {
        int row = bm + wm + mt * 16 + quad * 4 + r;
        float v = acc[mt][nt][r] + bv;
        if (OUTBF16)
          ((__hip_bfloat16*)Cv)[(size_t)row * N + col] = __float2bfloat16(v);
        else
          ((float*)Cv)[(size_t)row * N + col] = v;
      }
    }
  }
}

// ---------------- field: segment-sum of v * ||k|| into G bins (vectorized) ----------------
// KV: (16384, 2048) bf16; cols 0..1023 = k, 1024..2047 = v.  field: (B,G,D) f32
__global__ __launch_bounds__(256) void wv_field_kernel(
    const __hip_bfloat16* __restrict__ KV, float* __restrict__ field) {
  const int b = blockIdx.x, g = blockIdx.y;
  // contiguous row range [i0,i1) of this bin, from the exact f32 formula
  int i0 = (g * 4095 + 510) / 511;
  while (i0 > 0 && fidx_of(i0 - 1) >= g) --i0;
  while (i0 < NPOS && fidx_of(i0) < g) ++i0;
  int i1;
  if (g == GSZ - 1) i1 = NPOS;
  else {
    i1 = ((g + 1) * 4095 + 510) / 511;
    while (i1 > 0 && fidx_of(i1 - 1) >= g + 1) --i1;
    while (i1 < NPOS && fidx_of(i1) < g + 1) ++i1;
  }
  int cnt = i1 - i0;                 // 8 or 9
  if (cnt > 12) cnt = 12;
  __shared__ float km[12][16];       // [row][head]
  const int tid = threadIdx.x;
  if (tid < cnt * 16) {              // phase 1: ||k|| per (row, head), bf16x8 loads
    int r = tid >> 4, h = tid & 15;
    const unsigned short* kp = (const unsigned short*)KV + (size_t)(b * NPOS + i0 + r) * 2048 + h * 64;
    float s = 0.f;
#pragma unroll
    for (int e = 0; e < 64; e += 8) {
      bf16x8 v = *(const bf16x8*)(kp + e);
#pragma unroll
      for (int q = 0; q < 8; ++q) { float f = bf2f((unsigned short)v[q]); s += f * f; }
    }
    km[r][h] = sqrtf(s);
  }
  __syncthreads();
  if (tid < 128) {                   // phase 2: weighted v-sum, 8 cols/thread
    int c0 = tid * 8, h = c0 >> 6;
    float acc[8] = {0.f, 0.f, 0.f, 0.f, 0.f, 0.f, 0.f, 0.f};
    for (int r = 0; r < cnt; ++r) {
      float w = km[r][h];
      bf16x8 v = *(const bf16x8*)((const unsigned short*)KV + (size_t)(b * NPOS + i0 + r) * 2048 + 1024 + c0);
#pragma unroll
      for (int q = 0; q < 8; ++q) acc[q] += w * bf2f((unsigned short)v[q]);
    }
    float4* fp = (float4*)(field + ((size_t)(b * GSZ + g)) * DIM + c0);
    fp[0] = make_float4(acc[0], acc[1], acc[2], acc[3]);
    fp[1] = make_float4(acc[4], acc[5], acc[6], acc[7]);
  }
}

// ---------------- causal conv as EMA recurrence ----------------
// w_j = (1-a) a^{j-1}, a = e^{-1/3}  =>  o[n] = (1-a)*f[(n+257)&511] + a*o[n+1]
// 64-step warm-up (truncation a^64 ~ 5e-10). Grid (4,16,2), block 256 = 64c x 4 chunks.
__global__ __launch_bounds__(256) void conv_ema_kernel(
    const float* __restrict__ field, __hip_bfloat16* __restrict__ convb) {
  const int b = blockIdx.x, h = blockIdx.y;
  const int tid = threadIdx.x;
  const int c = tid & 63;
  const int chunk = blockIdx.z * 4 + (tid >> 6);   // 0..7
  const int n0 = chunk * 64;
  const float a = expf(-1.0f / 3.0f);
  const float w1 = 1.0f - a;
  const float* fb = field + (size_t)b * GSZ * DIM + h * 64 + c;
  float acc = 0.f;
#pragma unroll 4
  for (int n = n0 + 127; n >= n0 + 64; --n) {      // warm-up
    float f = fb[(size_t)((n + 257) & (GSZ - 1)) * DIM];
    acc = w1 * f + a * acc;
  }
#pragma unroll 4
  for (int n = n0 + 63; n >= n0; --n) {            // emit
    float f = fb[(size_t)((n + 257) & (GSZ - 1)) * DIM];
    acc = w1 * f + a * acc;
    convb[((size_t)(b * GSZ) + n) * DIM + h * 64 + c] = __float2bfloat16(acc);
  }
}

// ---------------- gather: d_out[b,n,:] = outc[b*512+fidx(n),:] ----------------
__global__ __launch_bounds__(256) void gather_out_kernel(
    const float* __restrict__ outc, float* __restrict__ out) {
  const int row = blockIdx.x;            // b*4096 + n
  const int b = row >> 12, n = row & (NPOS - 1);
  const int g = fidx_of(n);
  const float4* src = (const float4*)(outc + ((size_t)(b * GSZ) + g) * DIM);
  float4* dst = (float4*)(out + (size_t)row * DIM);
  dst[threadIdx.x] = src[threadIdx.x];
}

extern "C" void kernel_launch(void* const* d_in, const int* in_sizes, int n_in,
                              void* d_out, int out_size, void* d_ws, size_t ws_size,
                              hipStream_t stream) {
  (void)in_sizes; (void)n_in; (void)out_size; (void)ws_size;
  const float* x     = (const float*)d_in[0];
  // d_in[1]=q_w, d_in[2]=q_b: dead in the reference — skipped.
  const float* k_w   = (const float*)d_in[3];
  const float* k_b   = (const float*)d_in[4];
  const float* v_w   = (const float*)d_in[5];
  const float* v_b   = (const float*)d_in[6];
  const float* out_w = (const float*)d_in[7];
  const float* out_b = (const float*)d_in[8];

  char* p = (char*)d_ws;
  __hip_bfloat16* xb    = (__hip_bfloat16*)p;                                 // 32 MB (dead after KV GEMM)
  float*          outc  = (float*)p;          p += (size_t)16384 * 1024 * 2;  // reuses xb space: 8 MB
  __hip_bfloat16* kvwb  = (__hip_bfloat16*)p; p += (size_t)2048 * 1024 * 2;   // 4 MB
  __hip_bfloat16* outwb = (__hip_bfloat16*)p; p += (size_t)1024 * 1024 * 2;   // 2 MB
  __hip_bfloat16* KV    = (__hip_bfloat16*)p; p += (size_t)16384 * 2048 * 2;  // 64 MB
  float*          field = (float*)p;          p += (size_t)4 * 512 * 1024 * 4;// 8 MB
  __hip_bfloat16* convb = (__hip_bfloat16*)p;                                 // 4 MB

  cast_f32_to_bf16<<<16384, 256, 0, stream>>>(x, xb, 16384 * 1024);
  cast_f32_to_bf16<<<1024, 256, 0, stream>>>(k_w, kvwb, 1024 * 1024);
  cast_f32_to_bf16<<<1024, 256, 0, stream>>>(v_w, kvwb + 1024 * 1024, 1024 * 1024);
  cast_f32_to_bf16<<<1024, 256, 0, stream>>>(out_w, outwb, 1024 * 1024);

  // fused K+V projection: (16384x1024) @ (2048x1024)^T -> KV bf16
  gemm_bt<true><<<dim3(128, 16), 256, 0, stream>>>(xb, kvwb, k_b, v_b, KV, 2048);

  wv_field_kernel<<<dim3(4, 512), 256, 0, stream>>>(KV, field);
  conv_ema_kernel<<<dim3(4, 16, 2), 256, 0, stream>>>(field, convb);

  // dedup'd output GEMM: only 2048 distinct conv rows -> outc (f32), then gather
  gemm_bt<false><<<dim3(16, 8), 256, 0, stream>>>(convb, outwb, out_b, out_b, outc, 1024);
  gather_out_kernel<<<16384, 256, 0, stream>>>(outc, (float*)d_out);
}

// Round 3
// 283.468 us; speedup vs baseline: 1.2379x; 1.0444x over previous
//
#include <hip/hip_runtime.h>
#include <hip/hip_bf16.h>

// Problem constants (B=4, N=4096, D=1024, H=16, hd=64, G=512, sigma=3)
#define NPOS 4096
#define DIM  1024
#define GSZ  512

#define GAS __attribute__((address_space(1)))
#define LAS __attribute__((address_space(3)))

typedef __attribute__((ext_vector_type(8))) short bf16x8;   // 8 bf16 (4 VGPRs)
typedef __attribute__((ext_vector_type(4))) float f32x4;

__device__ __forceinline__ void async_load16(const void* g, void* l) {
  __builtin_amdgcn_global_load_lds((const GAS void*)g, (LAS void*)l, 16, 0, 0);
}

// Bit-exact replica of np: (arange(N,f32)/4095)*511 then trunc-to-int32.
__device__ __forceinline__ int fidx_of(int n) {
  return (int)(((float)n / 4095.0f) * 511.0f);
}

__device__ __forceinline__ float bf2f(unsigned short s) {
  union { unsigned u; float f; } v; v.u = ((unsigned)s) << 16; return v.f;
}

// exact [i0,i1) row-range of bin g under fidx_of
__device__ __forceinline__ void bin_range(int g, int& i0, int& i1) {
  i0 = (g * 4095 + 510) / 511;
  while (i0 > 0 && fidx_of(i0 - 1) >= g) --i0;
  while (i0 < NPOS && fidx_of(i0) < g) ++i0;
  if (g == GSZ - 1) { i1 = NPOS; return; }
  i1 = ((g + 1) * 4095 + 510) / 511;
  while (i1 > 0 && fidx_of(i1 - 1) >= g + 1) --i1;
  while (i1 < NPOS && fidx_of(i1) < g + 1) ++i1;
}

// ---------------- all f32->bf16 casts in one launch ----------------
// blocks [0,16384): x -> xb ; [16384,17408): k_w ; [17408,18432): v_w ; [18432,19456): out_w
__global__ __launch_bounds__(256) void cast_all(
    const float* __restrict__ x, const float* __restrict__ kw,
    const float* __restrict__ vw, const float* __restrict__ ow,
    __hip_bfloat16* __restrict__ xb, __hip_bfloat16* __restrict__ kvwb,
    __hip_bfloat16* __restrict__ outwb) {
  int blk = blockIdx.x;
  const float* src; __hip_bfloat16* dst; int off;
  if (blk < 16384)      { src = x;  dst = xb;              off = blk; }
  else if (blk < 17408) { src = kw; dst = kvwb;            off = blk - 16384; }
  else if (blk < 18432) { src = vw; dst = kvwb + 1048576;  off = blk - 17408; }
  else                  { src = ow; dst = outwb;           off = blk - 18432; }
  int i = (off * 256 + threadIdx.x) * 4;
  float4 f = *(const float4*)(src + i);
  ushort4 o;
  __hip_bfloat16 t;
  t = __float2bfloat16(f.x); o.x = *(unsigned short*)&t;
  t = __float2bfloat16(f.y); o.y = *(unsigned short*)&t;
  t = __float2bfloat16(f.z); o.z = *(unsigned short*)&t;
  t = __float2bfloat16(f.w); o.w = *(unsigned short*)&t;
  *(ushort4*)(dst + i) = o;
}

// ---------------- 128x128-tile bf16 MFMA GEMM (NT: C = A @ B^T), bf16 out ----------------
// A: M x K row-major; B: N x K row-major; bias per column (cols<1024 -> bias0)
__global__ __launch_bounds__(256) void gemm_bt(
    const __hip_bfloat16* __restrict__ A,
    const __hip_bfloat16* __restrict__ B,
    const float* __restrict__ bias0, const float* __restrict__ bias1,
    __hip_bfloat16* __restrict__ C, int N) {
  const int K = 1024;
  __shared__ __align__(16) __hip_bfloat16 As[128 * 32];
  __shared__ __align__(16) __hip_bfloat16 Bs[128 * 32];
  const int tid = threadIdx.x;
  const int bm = blockIdx.x * 128, bn = blockIdx.y * 128;

  const int srow = tid >> 2;          // 0..63
  const int scol = (tid & 3) * 8;     // 0,8,16,24
  const __hip_bfloat16* ap0 = A + (size_t)(bm + srow) * K + scol;
  const __hip_bfloat16* ap1 = A + (size_t)(bm + srow + 64) * K + scol;
  const __hip_bfloat16* bp0 = B + (size_t)(bn + srow) * K + scol;
  const __hip_bfloat16* bp1 = B + (size_t)(bn + srow + 64) * K + scol;
  __hip_bfloat16* as0 = &As[srow * 32 + scol];        // lane-ordered: tid*16B
  __hip_bfloat16* as1 = &As[(srow + 64) * 32 + scol];
  __hip_bfloat16* bs0 = &Bs[srow * 32 + scol];
  __hip_bfloat16* bs1 = &Bs[(srow + 64) * 32 + scol];

  const int wave = tid >> 6, lane = tid & 63;
  const int wm = (wave >> 1) * 64, wn = (wave & 1) * 64;
  const int m16 = lane & 15, quad = lane >> 4;

  f32x4 acc[4][4];
#pragma unroll
  for (int i = 0; i < 4; i++)
#pragma unroll
    for (int j = 0; j < 4; j++) acc[i][j] = (f32x4)0.f;

  for (int k0 = 0; k0 < K; k0 += 32) {
    async_load16(ap0 + k0, as0);
    async_load16(ap1 + k0, as1);
    async_load16(bp0 + k0, bs0);
    async_load16(bp1 + k0, bs1);
    __syncthreads();
    bf16x8 af[4], bfr[4];
#pragma unroll
    for (int mt = 0; mt < 4; mt++)
      af[mt] = *(const bf16x8*)&As[(wm + mt * 16 + m16) * 32 + quad * 8];
#pragma unroll
    for (int nt = 0; nt < 4; nt++)
      bfr[nt] = *(const bf16x8*)&Bs[(wn + nt * 16 + m16) * 32 + quad * 8];
#pragma unroll
    for (int mt = 0; mt < 4; mt++)
#pragma unroll
      for (int nt = 0; nt < 4; nt++)
        acc[mt][nt] = __builtin_amdgcn_mfma_f32_16x16x32_bf16(af[mt], bfr[nt], acc[mt][nt], 0, 0, 0);
    __syncthreads();
  }

  // epilogue: C/D layout col=lane&15, row=quad*4+reg (m89/m91-verified)
#pragma unroll
  for (int mt = 0; mt < 4; mt++) {
#pragma unroll
    for (int nt = 0; nt < 4; nt++) {
      int col = bn + wn + nt * 16 + m16;
      float bv = (col < 1024) ? bias0[col] : bias1[col - 1024];
#pragma unroll
      for (int r = 0; r < 4; r++) {
        int row = bm + wm + mt * 16 + quad * 4 + r;
        C[(size_t)row * N + col] = __float2bfloat16(acc[mt][nt][r] + bv);
      }
    }
  }
}

// ---------------- output GEMM, 64x128 tile, fused broadcast-gather epilogue ----------------
// A = convb (2048 x 1024 bf16), B = outwb (1024 x 1024 bf16), out f32 (B,N,D)
// Row R=b*512+g of A@B^T+bias is written to out[b, n, :] for all n with fidx(n)==g.
__global__ __launch_bounds__(256) void gemm_out_bcast(
    const __hip_bfloat16* __restrict__ A,
    const __hip_bfloat16* __restrict__ B,
    const float* __restrict__ bias,
    float* __restrict__ out) {
  const int K = 1024;
  __shared__ __align__(16) __hip_bfloat16 As[64 * 32];
  __shared__ __align__(16) __hip_bfloat16 Bs[128 * 32];
  const int tid = threadIdx.x;
  const int bm = blockIdx.x * 64, bn = blockIdx.y * 128;

  const int srow = tid >> 2;          // 0..63
  const int scol = (tid & 3) * 8;
  const __hip_bfloat16* ap0 = A + (size_t)(bm + srow) * K + scol;
  const __hip_bfloat16* bp0 = B + (size_t)(bn + srow) * K + scol;
  const __hip_bfloat16* bp1 = B + (size_t)(bn + srow + 64) * K + scol;
  __hip_bfloat16* as0 = &As[srow * 32 + scol];
  __hip_bfloat16* bs0 = &Bs[srow * 32 + scol];
  __hip_bfloat16* bs1 = &Bs[(srow + 64) * 32 + scol];

  const int wave = tid >> 6, lane = tid & 63;
  const int wm = (wave >> 1) * 32, wn = (wave & 1) * 64;   // 2x2 waves, 32x64 each
  const int m16 = lane & 15, quad = lane >> 4;

  f32x4 acc[2][4];
#pragma unroll
  for (int i = 0; i < 2; i++)
#pragma unroll
    for (int j = 0; j < 4; j++) acc[i][j] = (f32x4)0.f;

  for (int k0 = 0; k0 < K; k0 += 32) {
    async_load16(ap0 + k0, as0);
    async_load16(bp0 + k0, bs0);
    async_load16(bp1 + k0, bs1);
    __syncthreads();
    bf16x8 af[2], bfr[4];
#pragma unroll
    for (int mt = 0; mt < 2; mt++)
      af[mt] = *(const bf16x8*)&As[(wm + mt * 16 + m16) * 32 + quad * 8];
#pragma unroll
    for (int nt = 0; nt < 4; nt++)
      bfr[nt] = *(const bf16x8*)&Bs[(wn + nt * 16 + m16) * 32 + quad * 8];
#pragma unroll
    for (int mt = 0; mt < 2; mt++)
#pragma unroll
      for (int nt = 0; nt < 4; nt++)
        acc[mt][nt] = __builtin_amdgcn_mfma_f32_16x16x32_bf16(af[mt], bfr[nt], acc[mt][nt], 0, 0, 0);
    __syncthreads();
  }

  float bv[4];
#pragma unroll
  for (int nt = 0; nt < 4; nt++) bv[nt] = bias[bn + wn + nt * 16 + m16];

#pragma unroll
  for (int mt = 0; mt < 2; mt++) {
#pragma unroll
    for (int r = 0; r < 4; r++) {
      int row = bm + wm + mt * 16 + quad * 4 + r;   // = b*512 + g
      int b = row >> 9, g = row & (GSZ - 1);
      int i0, i1;
      bin_range(g, i0, i1);
      float v0 = acc[mt][0][r] + bv[0];
      float v1 = acc[mt][1][r] + bv[1];
      float v2 = acc[mt][2][r] + bv[2];
      float v3 = acc[mt][3][r] + bv[3];
      for (int n = i0; n < i1; ++n) {
        float* orow = out + ((size_t)(b * NPOS + n)) * DIM + bn + wn + m16;
        orow[0]  = v0;
        orow[16] = v1;
        orow[32] = v2;
        orow[48] = v3;
      }
    }
  }
}

// ---------------- field: segment-sum of v * ||k|| into G bins (vectorized) ----------------
// KV: (16384, 2048) bf16; cols 0..1023 = k, 1024..2047 = v.  field: (B,G,D) f32
__global__ __launch_bounds__(256) void wv_field_kernel(
    const __hip_bfloat16* __restrict__ KV, float* __restrict__ field) {
  const int b = blockIdx.x, g = blockIdx.y;
  int i0, i1;
  bin_range(g, i0, i1);
  int cnt = i1 - i0;                 // 8 or 9
  if (cnt > 12) cnt = 12;
  __shared__ float km[12][16];       // [row][head]
  const int tid = threadIdx.x;
  if (tid < cnt * 16) {              // phase 1: ||k|| per (row, head), bf16x8 loads
    int r = tid >> 4, h = tid & 15;
    const unsigned short* kp = (const unsigned short*)KV + (size_t)(b * NPOS + i0 + r) * 2048 + h * 64;
    float s = 0.f;
#pragma unroll
    for (int e = 0; e < 64; e += 8) {
      bf16x8 v = *(const bf16x8*)(kp + e);
#pragma unroll
      for (int q = 0; q < 8; ++q) { float f = bf2f((unsigned short)v[q]); s += f * f; }
    }
    km[r][h] = sqrtf(s);
  }
  __syncthreads();
  if (tid < 128) {                   // phase 2: weighted v-sum, 8 cols/thread
    int c0 = tid * 8, h = c0 >> 6;
    float acc[8] = {0.f, 0.f, 0.f, 0.f, 0.f, 0.f, 0.f, 0.f};
    for (int r = 0; r < cnt; ++r) {
      float w = km[r][h];
      bf16x8 v = *(const bf16x8*)((const unsigned short*)KV + (size_t)(b * NPOS + i0 + r) * 2048 + 1024 + c0);
#pragma unroll
      for (int q = 0; q < 8; ++q) acc[q] += w * bf2f((unsigned short)v[q]);
    }
    float4* fp = (float4*)(field + ((size_t)(b * GSZ + g)) * DIM + c0);
    fp[0] = make_float4(acc[0], acc[1], acc[2], acc[3]);
    fp[1] = make_float4(acc[4], acc[5], acc[6], acc[7]);
  }
}

// ---------------- causal conv as EMA recurrence ----------------
// w_j = (1-a) a^{j-1}, a = e^{-1/3}  =>  o[n] = (1-a)*f[(n+257)&511] + a*o[n+1]
// 64-step warm-up (truncation a^64 ~ 5e-10). Grid (4,16,2), block 256 = 64c x 4 chunks.
__global__ __launch_bounds__(256) void conv_ema_kernel(
    const float* __restrict__ field, __hip_bfloat16* __restrict__ convb) {
  const int b = blockIdx.x, h = blockIdx.y;
  const int tid = threadIdx.x;
  const int c = tid & 63;
  const int chunk = blockIdx.z * 4 + (tid >> 6);   // 0..7
  const int n0 = chunk * 64;
  const float a = expf(-1.0f / 3.0f);
  const float w1 = 1.0f - a;
  const float* fb = field + (size_t)b * GSZ * DIM + h * 64 + c;
  float acc = 0.f;
#pragma unroll 4
  for (int n = n0 + 127; n >= n0 + 64; --n) {      // warm-up
    float f = fb[(size_t)((n + 257) & (GSZ - 1)) * DIM];
    acc = w1 * f + a * acc;
  }
#pragma unroll 4
  for (int n = n0 + 63; n >= n0; --n) {            // emit
    float f = fb[(size_t)((n + 257) & (GSZ - 1)) * DIM];
    acc = w1 * f + a * acc;
    convb[((size_t)(b * GSZ) + n) * DIM + h * 64 + c] = __float2bfloat16(acc);
  }
}

extern "C" void kernel_launch(void* const* d_in, const int* in_sizes, int n_in,
                              void* d_out, int out_size, void* d_ws, size_t ws_size,
                              hipStream_t stream) {
  (void)in_sizes; (void)n_in; (void)out_size; (void)ws_size;
  const float* x     = (const float*)d_in[0];
  // d_in[1]=q_w, d_in[2]=q_b: dead in the reference — skipped.
  const float* k_w   = (const float*)d_in[3];
  const float* k_b   = (const float*)d_in[4];
  const float* v_w   = (const float*)d_in[5];
  const float* v_b   = (const float*)d_in[6];
  const float* out_w = (const float*)d_in[7];
  const float* out_b = (const float*)d_in[8];

  char* p = (char*)d_ws;
  __hip_bfloat16* xb    = (__hip_bfloat16*)p; p += (size_t)16384 * 1024 * 2;  // 32 MB
  __hip_bfloat16* kvwb  = (__hip_bfloat16*)p; p += (size_t)2048 * 1024 * 2;   // 4 MB
  __hip_bfloat16* outwb = (__hip_bfloat16*)p; p += (size_t)1024 * 1024 * 2;   // 2 MB
  __hip_bfloat16* KV    = (__hip_bfloat16*)p; p += (size_t)16384 * 2048 * 2;  // 64 MB
  float*          field = (float*)p;          p += (size_t)4 * 512 * 1024 * 4;// 8 MB
  __hip_bfloat16* convb = (__hip_bfloat16*)p;                                 // 4 MB

  cast_all<<<19456, 256, 0, stream>>>(x, k_w, v_w, out_w, xb, kvwb, outwb);

  // fused K+V projection: (16384x1024) @ (2048x1024)^T -> KV bf16
  gemm_bt<<<dim3(128, 16), 256, 0, stream>>>(xb, kvwb, k_b, v_b, KV, 2048);

  wv_field_kernel<<<dim3(4, 512), 256, 0, stream>>>(KV, field);
  conv_ema_kernel<<<dim3(4, 16, 2), 256, 0, stream>>>(field, convb);

  // dedup'd output GEMM (2048 distinct rows) with fused broadcast-gather into d_out
  gemm_out_bcast<<<dim3(32, 8), 256, 0, stream>>>(convb, outwb, out_b, (float*)d_out);
}